// Round 8
// baseline (173.991 us; speedup 1.0000x reference)
//
#include <hip/hip_runtime.h>
#include <hip/hip_bf16.h>

// Workspace layout (needs 34 MB):
//   [0, 2MB)    Ut : U^T as bf16, Ut[n][k] = bf16(U[k][n])
//   [2MB, 34MB) xg : gathered x as bf16, xg[b][i] = bf16(x[b][ans[b][i]])
#define WS_UT    ((size_t)0)
#define WS_XG    ((size_t)2*1024*1024)

typedef __attribute__((ext_vector_type(8))) short short8;
typedef __attribute__((ext_vector_type(4))) float floatx4;

__device__ __forceinline__ void load_lds16(const void* g, void* l) {
  __builtin_amdgcn_global_load_lds(
      (const __attribute__((address_space(1))) void*)g,
      (__attribute__((address_space(3))) void*)l, 16, 0, 0);
}

__device__ __forceinline__ unsigned short f2bf(float f) {
  __hip_bfloat16 h = __float2bfloat16(f);
  return __builtin_bit_cast(unsigned short, h);
}
__device__ __forceinline__ float bf2f(unsigned short u) {
  return __uint_as_float(((unsigned)u) << 16);
}

// ---------------- K1: prep (Ut = bf16(U^T)) + gather (xg) in one launch ----------------
__global__ void __launch_bounds__(256) prep_gather_k(const float* __restrict__ U,
                                                     const float* __restrict__ x,
                                                     const int* __restrict__ perm,
                                                     const int* __restrict__ prand,
                                                     unsigned short* __restrict__ ut,
                                                     unsigned short* __restrict__ xg) {
  __shared__ __align__(16) char smem[64 * 65 * 4];
  if (blockIdx.x < 256) {
    float (*tile)[65] = (float (*)[65])smem;
    const int tn = (blockIdx.x & 15) * 64;
    const int tk = (blockIdx.x >> 4) * 64;
    const int r = threadIdx.x >> 6;
    const int c = threadIdx.x & 63;
    for (int s = 0; s < 16; ++s)
      tile[s * 4 + r][c] = U[(size_t)(tk + s * 4 + r) * 1024 + tn + c];
    __syncthreads();
    for (int s = 0; s < 16; ++s)
      ut[(size_t)(tn + s * 4 + r) * 1024 + tk + c] = f2bf(tile[c][s * 4 + r]);
    return;
  }
  float (*xrow)[1024] = (float (*)[1024])smem;
  const int w = threadIdx.x >> 6, lane = threadIdx.x & 63;
  const int row = (blockIdx.x - 256) * 4 + w;
  const unsigned mult = ((unsigned)prand[0] * 6u) & 1023u;
  const unsigned br = (((unsigned)row & 1023u) * mult + 1u) & 1023u;
  const float* xr = x + (size_t)row * 1024;
  unsigned short* xo = xg + (size_t)row * 1024;
  for (int t = 0; t < 4; ++t) {
    floatx4 v = *(const floatx4*)(xr + t * 256 + lane * 4);
    *(floatx4*)(&xrow[w][t * 256 + lane * 4]) = v;
  }
  __syncthreads();
  for (int t = 0; t < 4; ++t) {
    int i0 = t * 256 + lane * 4;
    int4 p = *(const int4*)(perm + i0);
    ushort4 o;
    o.x = f2bf(xrow[w][((unsigned)p.x * br) & 1023u]);
    o.y = f2bf(xrow[w][((unsigned)p.y * br) & 1023u]);
    o.z = f2bf(xrow[w][((unsigned)p.z * br) & 1023u]);
    o.w = f2bf(xrow[w][((unsigned)p.w * br) & 1023u]);
    *(ushort4*)(xo + i0) = o;
  }
}

// ---------------- K2: fused GEMM + scatter ----------------
// M=64 x N=1024, grid 256 (1 block/CU), 512 threads (8 waves, 2/SIMD ->
// 256 unified regs/wave). Round-8 changes vs R7 (61us, MfmaUtil 21%):
//  * TRUE B double-buffer, BK=32: per-wave 8KB slices x2 (128KB) + A
//    triple-buffer (3x4KB) = 140KB. stage(h+1) issues at the TOP of step h
//    into the other buffer -> L2 delivery overlaps compute+barrier (R7
//    gated the stage behind lgkmcnt(0) into the SAME slice -> serial).
//  * K-ROTATION: block starts its k-loop at rot=blockIdx.x&31 (sum order
//    irrelevant). Without it all 256 blocks hammer the same 128KB window
//    of ut simultaneously -> L2 bank hotspotting (~3x delivery slowdown).
//  * One barrier/step; counted vmcnt(9|8) keeps the in-flight buffer's
//    loads pending ACROSS the barrier (w<4 also stage A, hence 9 vs 8).
__global__ void __launch_bounds__(512, 2) gemm_scatter_k(
    const unsigned short* __restrict__ xg,
    const unsigned short* __restrict__ ut,
    const int* __restrict__ perm,
    const int* __restrict__ prand,
    float* __restrict__ out) {
  extern __shared__ __align__(16) char smem[];
  // [0,12K): A abuf[3] 4KB each. [12K,140K): B bbuf[2] 64KB each (8KB/wave).
  const int tid = threadIdx.x;
  const int w = tid >> 6, lane = tid & 63;
  const int m = lane & 15, q = lane >> 4;
  const int R0 = blockIdx.x * 64;
  const int wn = w * 128;
  const int rot = blockIdx.x & 31;

  // 64B rows, 4 chunks; logical chunk q at physical slot q^(m&3)
  const int swz = (q ^ (m & 3)) * 16;
  const int rdA = m * 64 + swz;                     // + p*4096 + i*1024
  const int rdB = 12288 + w * 8192 + m * 64 + swz;  // + bb + jj*1024

  // staging: 1KB instr = 16 rows x 4 slots; row=lane>>2, slot=lane&3;
  // linear LDS dest, inverse-swizzled global source chunk = slot^(row&3)
  const int sr = lane >> 2;
  const int schunk = ((lane & 3) ^ (sr & 3)) * 8;  // in shorts
  const unsigned short* asrc = xg + (size_t)(R0 + w * 16 + sr) * 1024 + schunk;  // w<4
  const unsigned short* bsrc = ut + (size_t)(wn + sr) * 1024 + schunk;
  char* adst = smem + w * 1024 + lane * 16;          // + p*4096
  char* bdst = smem + 12288 + w * 8192 + lane * 16;  // + bb + t*1024

  floatx4 acc[4][8];
#pragma unroll
  for (int i = 0; i < 4; ++i)
#pragma unroll
    for (int jj = 0; jj < 8; ++jj) acc[i][jj] = (floatx4)0.0f;

  auto stageB = [&](int buf, int kp) {
#pragma unroll
    for (int t = 0; t < 8; ++t)
      load_lds16(bsrc + (size_t)t * 16384 + kp * 32, bdst + buf + t * 1024);
  };
  auto compute = [&](int aoff, int boff) {
    short8 a[4], b[8];
#pragma unroll
    for (int i = 0; i < 4; ++i)
      a[i] = *(const short8*)(smem + aoff + i * 1024 + rdA);
#pragma unroll
    for (int jj = 0; jj < 8; ++jj)
      b[jj] = *(const short8*)(smem + boff + jj * 1024 + rdB);
    __builtin_amdgcn_s_setprio(1);
#pragma unroll
    for (int i = 0; i < 4; ++i)
#pragma unroll
      for (int jj = 0; jj < 8; ++jj)
        acc[i][jj] = __builtin_amdgcn_mfma_f32_16x16x32_bf16(b[jj], a[i],
                                                             acc[i][jj], 0, 0, 0);
    __builtin_amdgcn_s_setprio(0);
    asm volatile("s_waitcnt lgkmcnt(0)" ::: "memory");  // reads done pre-restage
    __builtin_amdgcn_sched_barrier(0);
  };

  // prologue: A(0)->p0, A(1)->p1 (w<4, BEFORE B so h=0's vmcnt retires them),
  // then B(0)->buf0
  int kpn = (rot + 1) & 31, kpn2 = (rot + 2) & 31;
  if (w < 4) {
    load_lds16(asrc + rot * 32, adst);
    load_lds16(asrc + kpn * 32, adst + 4096);
  }
  stageB(0, rot);

  int pc = 0, pn = 4096, pn2 = 8192;  // abuf rotation (step h reads pc)
  int bb = 0;                          // bbuf of step h: {0, 65536}
#pragma unroll 1
  for (int h = 0; h < 30; ++h) {
    stageB(bb ^ 65536, kpn);                    // B(h+1), other buffer
    if (w < 4) {
      load_lds16(asrc + kpn2 * 32, adst + pn2); // A(h+2)
      asm volatile("s_waitcnt vmcnt(9)" ::: "memory");  // B(h),A(h) landed
    } else {
      asm volatile("s_waitcnt vmcnt(8)" ::: "memory");
    }
    __builtin_amdgcn_sched_barrier(0);
    __builtin_amdgcn_s_barrier();
    __builtin_amdgcn_sched_barrier(0);
    compute(pc, bb);
    int t = pc; pc = pn; pn = pn2; pn2 = t;
    bb ^= 65536;
    kpn = kpn2; kpn2 = (kpn2 + 1) & 31;
  }
  // h = 30: stage B(31) only
  stageB(bb ^ 65536, kpn);
  if (w < 4) asm volatile("s_waitcnt vmcnt(9)" ::: "memory");
  else       asm volatile("s_waitcnt vmcnt(8)" ::: "memory");
  __builtin_amdgcn_sched_barrier(0);
  __builtin_amdgcn_s_barrier();
  __builtin_amdgcn_sched_barrier(0);
  compute(pc, bb);
  { int t = pc; pc = pn; pn = pn2; pn2 = t; }
  bb ^= 65536;
  // h = 31: no stage, full drain
  asm volatile("s_waitcnt vmcnt(0)" ::: "memory");
  __builtin_amdgcn_sched_barrier(0);
  __builtin_amdgcn_s_barrier();
  __builtin_amdgcn_sched_barrier(0);
  compute(pc, bb);
  __syncthreads();  // all compute retired before sbuf overwrites buffers

  // ---- epilogue: 8 passes of 8 rows; value = rs*y + xg, scatter via LDS ----
  // Mapping (verified R4-R7): acc[i][jj][r] = y[R0+i*16+m][wn+jj*16+q*4+r].
  const unsigned mult = ((unsigned)prand[0] * 6u) & 1023u;
  const float rs = 0.33333334f;  // sqrt(0.1/0.9) = 1/3
  float* sbuf = (float*)smem;    // [8][1024] f32 = 32KB
#pragma unroll
  for (int p = 0; p < 8; ++p) {
    const int i = p >> 1;
    if ((m >> 3) == (p & 1)) {  // lane's rows i*16+m fall in [p*8, p*8+8)
      const int r = i * 16 + m;
      const unsigned br = (((unsigned)(R0 + r) & 1023u) * mult + 1u) & 1023u;
      const unsigned short* xr = xg + (size_t)(R0 + r) * 1024;
#pragma unroll
      for (int jj = 0; jj < 8; ++jj) {
        const int j0 = wn + jj * 16 + q * 4;
        const int4 p4 = *(const int4*)(perm + j0);
        const ushort4 x4 = *(const ushort4*)(xr + j0);
        sbuf[((r & 7) << 10) + (((unsigned)p4.x * br) & 1023u)] = rs * acc[i][jj][0] + bf2f(x4.x);
        sbuf[((r & 7) << 10) + (((unsigned)p4.y * br) & 1023u)] = rs * acc[i][jj][1] + bf2f(x4.y);
        sbuf[((r & 7) << 10) + (((unsigned)p4.z * br) & 1023u)] = rs * acc[i][jj][2] + bf2f(x4.z);
        sbuf[((r & 7) << 10) + (((unsigned)p4.w * br) & 1023u)] = rs * acc[i][jj][3] + bf2f(x4.w);
      }
    }
    __syncthreads();
    float* orow = out + (size_t)(R0 + p * 8) * 1024;
#pragma unroll
    for (int v = 0; v < 4; ++v) {
      const int f = v * 512 + tid;  // float4 idx in [0,2048)
      *(floatx4*)(orow + (size_t)f * 4) = *(const floatx4*)(sbuf + (size_t)f * 4);
    }
    if (p < 7) __syncthreads();
  }
}

extern "C" void kernel_launch(void* const* d_in, const int* in_sizes, int n_in,
                              void* d_out, int out_size, void* d_ws, size_t ws_size,
                              hipStream_t stream) {
  const float* x = (const float*)d_in[0];
  const float* U = (const float*)d_in[1];
  const int* perm = (const int*)d_in[2];
  const int* prand = (const int*)d_in[3];
  float* out = (float*)d_out;
  char* ws = (char*)d_ws;
  unsigned short* ut = (unsigned short*)(ws + WS_UT);
  unsigned short* xg = (unsigned short*)(ws + WS_XG);

  // 140KB dynamic LDS for K2
  hipFuncSetAttribute((const void*)gemm_scatter_k,
                      hipFuncAttributeMaxDynamicSharedMemorySize, 143360);

  prep_gather_k<<<256 + 4096, 256, 0, stream>>>(U, x, perm, prand, ut, xg);
  gemm_scatter_k<<<256, 512, 143360, stream>>>(xg, ut, perm, prand, out);
}